// Round 2
// baseline (362.403 us; speedup 1.0000x reference)
//
#include <hip/hip_runtime.h>

// FeatureCorrelation: B=8192 rows x 3 steps x D=2048 fp32.
// Per row: 9 scalar reductions -> 12 weights -> 3 linear-combo outputs.
// Pure streaming: 201 MB in + 201 MB out; floor ~64 us @ 6.3 TB/s achievable.
//
// R5: software-pipelined persistent waves.
//  - R4 (121 us rocprof, 2.4 TB/s): wave-per-row, but VGPR=104 proves pos loads
//    were serialized into the add loop (vmcnt waits), and the wave was
//    bulk-synchronous: load burst -> drain -> ~2600cy compute with memory idle.
//  - Now: 512 blocks (2/CU resident, 2 waves/SIMD), each wave grid-strides
//    4 rows with a 2-deep ping-pong pipeline: row k+1's 24 global loads are
//    in flight across row k's entire reduce/weights/store phase.
//  - pos (24 KB) staged in LDS once per block: pos adds are ds_read (lgkmcnt),
//    fully decoupled from the vmcnt prefetch queue -- a pos wait can no longer
//    drain the prefetch.
//  - NT stores unchanged from R4 (isolate the structural change).

constexpr int D   = 2048;
constexpr int TPB = 256;                  // 4 waves per block
constexpr int WPB = TPB / 64;             // waves per block
constexpr int NC  = D / (64 * 4);         // fvec4 chunks per lane per vector = 8
constexpr float EPS_PD = 1e-6f;
constexpr float EPS_CS = 1e-8f;

using fvec4 = __attribute__((ext_vector_type(4))) float;

__global__ __launch_bounds__(TPB, 2) void feat_corr_kernel(
    const float* __restrict__ feat,
    const float* __restrict__ pos,
    float* __restrict__ out,
    int B, int NW)                         // NW = total waves in grid
{
    // ---- Stage pos (24 KB) into LDS once per block.
    __shared__ float pshared[3 * D];
    {
        const fvec4* ps = (const fvec4*)pos;
        fvec4*       pd = (fvec4*)pshared;
        for (int i = threadIdx.x; i < 3 * D / 4; i += TPB)
            pd[i] = ps[i];
    }
    __syncthreads();                       // only barrier in the kernel

    const int lane = threadIdx.x & 63;
    const int gw   = blockIdx.x * WPB + (threadIdx.x >> 6);

    const fvec4* p1 = (const fvec4*)pshared;
    const fvec4* p2 = p1 + D / 4;
    const fvec4* p3 = p2 + D / 4;

    // Ping-pong row buffers: 2 x 24 fvec4 = 192 VGPR of data. Static indexing
    // only (runtime-indexed ext_vector arrays go to scratch).
    fvec4 xA1[NC], xA2[NC], xA3[NC];
    fvec4 xB1[NC], xB2[NC], xB3[NC];

    auto load_row = [&](fvec4 (&x1)[NC], fvec4 (&x2)[NC], fvec4 (&x3)[NC], int b) {
        const fvec4* r1 = (const fvec4*)(feat + (size_t)b * (3 * D));
        const fvec4* r2 = r1 + D / 4;
        const fvec4* r3 = r2 + D / 4;
#pragma unroll
        for (int j = 0; j < NC; ++j) x1[j] = r1[j * 64 + lane];
#pragma unroll
        for (int j = 0; j < NC; ++j) x2[j] = r2[j * 64 + lane];
#pragma unroll
        for (int j = 0; j < NC; ++j) x3[j] = r3[j * 64 + lane];
    };

    auto process_row = [&](fvec4 (&x1)[NC], fvec4 (&x2)[NC], fvec4 (&x3)[NC], int b) {
        // pos add from LDS (lgkm queue -- does not touch the vmcnt prefetch).
#pragma unroll
        for (int j = 0; j < NC; ++j) {
            x1[j] += p1[j * 64 + lane];
            x2[j] += p2[j * 64 + lane];
            x3[j] += p3[j * 64 + lane];
        }

        // 9 per-lane partial sums over 32 elements per vector.
        float n1s = 0.f, n2s = 0.f, n3s = 0.f;
        float d12 = 0.f, d13 = 0.f, d23 = 0.f;
        float s1  = 0.f, s2  = 0.f, s3  = 0.f;
#pragma unroll
        for (int j = 0; j < NC; ++j) {
#pragma unroll
            for (int k = 0; k < 4; ++k) {
                const float u = x1[j][k], w = x2[j][k], z = x3[j][k];
                n1s = fmaf(u, u, n1s);
                n2s = fmaf(w, w, n2s);
                n3s = fmaf(z, z, n3s);
                d12 = fmaf(u, w, d12);
                d13 = fmaf(u, z, d13);
                d23 = fmaf(w, z, d23);
                s1 += u; s2 += w; s3 += z;
            }
        }

        // Full-wave butterfly: every lane ends with the 9 totals.
        float vals[9] = {n1s, n2s, n3s, d12, d13, d23, s1, s2, s3};
#pragma unroll
        for (int off = 1; off < 64; off <<= 1) {
#pragma unroll
            for (int k = 0; k < 9; ++k)
                vals[k] += __shfl_xor(vals[k], off, 64);
        }

        const float N1s = vals[0], N2s = vals[1], N3s = vals[2];
        const float D12 = vals[3], D13 = vals[4], D23 = vals[5];
        const float S1  = vals[6], S2  = vals[7], S3  = vals[8];

        const float n1 = fmaxf(sqrtf(N1s), EPS_CS);
        const float n2 = fmaxf(sqrtf(N2s), EPS_CS);
        const float n3 = fmaxf(sqrtf(N3s), EPS_CS);

        const float c12 = 0.5f + 0.5f * (D12 / (n1 * n2));  // cosine terms
        const float c13 = 0.5f + 0.5f * (D13 / (n1 * n3));
        const float c23 = 0.5f + 0.5f * (D23 / (n2 * n3));

        const float sq12 = N1s + N2s - 2.f * D12;           // sum((fi-fj)^2)
        const float sq13 = N1s + N3s - 2.f * D13;
        const float sq23 = N2s + N3s - 2.f * D23;
        const float De2  = (float)D * EPS_PD * EPS_PD;

        // 1/(1+sqrt(sum((fi-fj+eps)^2))): eps inside the square -> sign-dependent
        auto wdist = [&](float sqd, float ssum) {
            return 1.0f / (1.0f + sqrtf(sqd + 2.f * EPS_PD * ssum + De2));
        };
        const float w12 = wdist(sq12, S1 - S2);
        const float w21 = wdist(sq12, S2 - S1);
        const float w13 = wdist(sq13, S1 - S3);
        const float w31 = wdist(sq13, S3 - S1);
        const float w23 = wdist(sq23, S2 - S3);
        const float w32 = wdist(sq23, S3 - S2);

        // o1 = f1 + (w12+c12) f2 + (w13+c13) f3   (etc., cyclic)
        const float g1b = w12 + c12, g1c = w13 + c13;
        const float g2a = w21 + c12, g2c = w23 + c23;
        const float g3a = w31 + c13, g3b = w32 + c23;

        const size_t row = (size_t)b * (3 * D);
        fvec4* o1 = (fvec4*)(out + row);
        fvec4* o2 = o1 + D / 4;
        fvec4* o3 = o2 + D / 4;
#pragma unroll
        for (int j = 0; j < NC; ++j) {
            const int idx = j * 64 + lane;
            fvec4 q1 = x1[j] + g1b * x2[j] + g1c * x3[j];
            fvec4 q2 = x2[j] + g2a * x1[j] + g2c * x3[j];
            fvec4 q3 = x3[j] + g3a * x1[j] + g3b * x2[j];
            __builtin_nontemporal_store(q1, o1 + idx);
            __builtin_nontemporal_store(q2, o2 + idx);
            __builtin_nontemporal_store(q3, o3 + idx);
        }
    };

    // ---- 2-deep pipeline over this wave's rows: gw, gw+NW, gw+2NW, ...
    int r = gw;
    if (r >= B) return;                    // after the barrier: deadlock-safe
    load_row(xA1, xA2, xA3, r);
    while (true) {
        const int rB = r + NW;
        if (rB < B) load_row(xB1, xB2, xB3, rB);   // prefetch issue (no wait)
        process_row(xA1, xA2, xA3, r);             // waits only A's loads
        if (rB >= B) break;
        const int rn = r + 2 * NW;
        if (rn < B) load_row(xA1, xA2, xA3, rn);   // prefetch issue
        process_row(xB1, xB2, xB3, rB);            // waits only B's loads
        if (rn >= B) break;
        r = rn;
    }
}

extern "C" void kernel_launch(void* const* d_in, const int* in_sizes, int n_in,
                              void* d_out, int out_size, void* d_ws, size_t ws_size,
                              hipStream_t stream) {
    const float* feat = (const float*)d_in[0];
    const float* pos  = (const float*)d_in[1];
    float* out        = (float*)d_out;
    const int B = in_sizes[0] / (3 * D);   // rows (element-count semantics, verified R4)
    int blocks = (B + WPB - 1) / WPB;
    if (blocks > 512) blocks = 512;        // persistent: 2 blocks/CU at 2 waves/SIMD
    const int NW = blocks * WPB;
    feat_corr_kernel<<<blocks, TPB, 0, stream>>>(feat, pos, out, B, NW);
}